// Round 6
// baseline (221.917 us; speedup 1.0000x reference)
//
#include <hip/hip_runtime.h>
#include <math.h>

#define N_NODES 100000
#define N_EDGES 6400000
#define K_BINS  3
#define BIN_SZ  33336          // ceil(N_NODES/3) rounded to /4
#define BIN_ALLOC (BIN_SZ + 64) // +64 per-lane dummy slots; 133,600 B LDS
#define BLOCK   1024
#define NXCD    8
#define LOG2_10 3.321928094887362f

// R6: branchless matched-edge path. R3/R5 cross-round analysis showed the
// edge kernel is bound by MATCHED-edge throughput (~6.4 cy/match, invariant
// across K=5/K=3), i.e. the per-slot `if(match){gather; waitcnt; ds_add}`
// serialization -- the compiler can't clause gathers across exec-mask
// branches (R2: VGPR stayed 32). Branchless version: clamp gather index to 0
// for unmatched lanes (broadcast line, ~free), clamp LDS index to a per-lane
// dummy slot (2-way bank alias = free, m136), always issue mul + ds_add.
// All 16 gathers per iteration become one load clause with a single vmcnt.
__global__ __launch_bounds__(BLOCK, 4) void edge_bin_kernel(
        const float* __restrict__ rates,
        const float* __restrict__ weights,
        const int* __restrict__ src,
        const int* __restrict__ dst,
        float* __restrict__ part,      // [n_chunks][N_NODES]
        int n_chunks, int edges_per_chunk) {
    __shared__ float bin[BIN_ALLOC];

    // Bijective XCD swizzle (m204): contiguous vbids per XCD => the 3 sibling
    // bin-blocks of a chunk share an XCD's L2 (R3-verified: FETCH 189->43 MB).
    const int nb  = gridDim.x;
    const int hb  = blockIdx.x;
    const int q   = nb / NXCD, r = nb % NXCD;
    const int xcd = hb % NXCD, pos = hb / NXCD;
    const int vbid = (xcd < r ? xcd * (q + 1) : r * (q + 1) + (xcd - r) * q) + pos;

    const int b = vbid % K_BINS;
    const int c = vbid / K_BINS;
    const int base_node = b * BIN_SZ;
    const int dummy = BIN_SZ + (int)(threadIdx.x & 63);

    // Vectorized zero-init (including dummy slots).
    {
        float4* bz = (float4*)bin;
        const float4 z = make_float4(0.f, 0.f, 0.f, 0.f);
        for (int i = threadIdx.x; i < (BIN_ALLOC >> 2); i += BLOCK) bz[i] = z;
    }
    __syncthreads();

    const long e0 = (long)c * edges_per_chunk;
    const int nq = edges_per_chunk >> 4;              // groups of 16 edges
    const int4*   s4 = (const int4*)(src + e0);
    const int4*   d4 = (const int4*)(dst + e0);
    const float4* w4 = (const float4*)(weights + e0);

#define LANE_IDX(dv, sv, aout, iout)                                   \
    {   unsigned ex = (unsigned)((dv) - base_node);                    \
        bool m = ex < BIN_SZ;                                          \
        (aout) = m ? (sv) : 0;                                         \
        (iout) = m ? (int)ex : dummy; }

    for (int i = threadIdx.x; i < nq; i += BLOCK) {
        const int4*   dp = d4 + 4 * i;
        const int4*   sp = s4 + 4 * i;
        const float4* wp = w4 + 4 * i;
        int4   d0 = dp[0], d1 = dp[1], d2 = dp[2], d3 = dp[3];
        int4   sA = sp[0], sB = sp[1], sC = sp[2], sD = sp[3];
        float4 wA = wp[0], wB = wp[1], wC = wp[2], wD = wp[3];

        // Phase 1: all 16 (gather-addr, lds-addr) pairs, branchless.
        int a0,a1,a2,a3,a4,a5,a6,a7,a8,a9,a10,a11,a12,a13,a14,a15;
        int i0,i1,i2,i3,i4,i5,i6,i7,i8,i9,i10,i11,i12,i13,i14,i15;
        LANE_IDX(d0.x, sA.x, a0,  i0);  LANE_IDX(d0.y, sA.y, a1,  i1);
        LANE_IDX(d0.z, sA.z, a2,  i2);  LANE_IDX(d0.w, sA.w, a3,  i3);
        LANE_IDX(d1.x, sB.x, a4,  i4);  LANE_IDX(d1.y, sB.y, a5,  i5);
        LANE_IDX(d1.z, sB.z, a6,  i6);  LANE_IDX(d1.w, sB.w, a7,  i7);
        LANE_IDX(d2.x, sC.x, a8,  i8);  LANE_IDX(d2.y, sC.y, a9,  i9);
        LANE_IDX(d2.z, sC.z, a10, i10); LANE_IDX(d2.w, sC.w, a11, i11);
        LANE_IDX(d3.x, sD.x, a12, i12); LANE_IDX(d3.y, sD.y, a13, i13);
        LANE_IDX(d3.z, sD.z, a14, i14); LANE_IDX(d3.w, sD.w, a15, i15);

        // Phase 2: 16 unconditional gathers -- one clause, one vmcnt wait.
        float r0 = rates[a0],  r1 = rates[a1],  r2 = rates[a2],  r3 = rates[a3];
        float r4 = rates[a4],  r5 = rates[a5],  r6 = rates[a6],  r7 = rates[a7];
        float r8 = rates[a8],  r9 = rates[a9],  r10= rates[a10], r11= rates[a11];
        float r12= rates[a12], r13= rates[a13], r14= rates[a14], r15= rates[a15];

        // Phase 3: 16 unconditional LDS atomics (no-return ds_add_f32).
        atomicAdd(&bin[i0],  r0  * wA.x); atomicAdd(&bin[i1],  r1  * wA.y);
        atomicAdd(&bin[i2],  r2  * wA.z); atomicAdd(&bin[i3],  r3  * wA.w);
        atomicAdd(&bin[i4],  r4  * wB.x); atomicAdd(&bin[i5],  r5  * wB.y);
        atomicAdd(&bin[i6],  r6  * wB.z); atomicAdd(&bin[i7],  r7  * wB.w);
        atomicAdd(&bin[i8],  r8  * wC.x); atomicAdd(&bin[i9],  r9  * wC.y);
        atomicAdd(&bin[i10], r10 * wC.z); atomicAdd(&bin[i11], r11 * wC.w);
        atomicAdd(&bin[i12], r12 * wD.x); atomicAdd(&bin[i13], r13 * wD.y);
        atomicAdd(&bin[i14], r14 * wD.z); atomicAdd(&bin[i15], r15 * wD.w);
    }
#undef LANE_IDX
    __syncthreads();

    // Vectorized flush, CLAMPED to the row (last bin holds 33,328 nodes;
    // writing all BIN_SZ would race with the next chunk-row's bin-0 flush).
    const int flush_n = min(BIN_SZ, N_NODES - base_node);
    float4* outp = (float4*)(part + (size_t)c * N_NODES + base_node);
    const float4* binv = (const float4*)bin;
    for (int i = threadIdx.x; i < (flush_n >> 2); i += BLOCK) {
        outp[i] = binv[i];
    }
}

// Node epilogue: sum the n_chunks copies, then
// out[v] = (-r + 10^gain * tanh((is_input ? ext : syn) + baseline)) / tau
__global__ void node_kernel(const float* __restrict__ rates,
                            const float* __restrict__ gain,
                            const float* __restrict__ time_constant,
                            const float* __restrict__ baseline,
                            const float* __restrict__ ext_input,
                            const int*   __restrict__ is_input,
                            const float* __restrict__ part,
                            float* __restrict__ out,
                            int n_chunks) {
    int v = blockIdx.x * blockDim.x + threadIdx.x;
    if (v >= N_NODES) return;
    float s0 = 0.f, s1 = 0.f, s2 = 0.f, s3 = 0.f;
    float s4 = 0.f, s5 = 0.f, s6 = 0.f, s7 = 0.f;
    int k = 0;
    for (; k + 7 < n_chunks; k += 8) {
        s0 += part[(size_t)(k + 0) * N_NODES + v];
        s1 += part[(size_t)(k + 1) * N_NODES + v];
        s2 += part[(size_t)(k + 2) * N_NODES + v];
        s3 += part[(size_t)(k + 3) * N_NODES + v];
        s4 += part[(size_t)(k + 4) * N_NODES + v];
        s5 += part[(size_t)(k + 5) * N_NODES + v];
        s6 += part[(size_t)(k + 6) * N_NODES + v];
        s7 += part[(size_t)(k + 7) * N_NODES + v];
    }
    for (; k < n_chunks; ++k) s0 += part[(size_t)k * N_NODES + v];
    float s = ((s0 + s1) + (s2 + s3)) + ((s4 + s5) + (s6 + s7));
    float total = (is_input[v] != 0 ? ext_input[v] : s) + baseline[v];
    float act = tanhf(total);
    float g = exp2f(gain[v] * LOG2_10);   // 10^gain
    out[v] = (-rates[v] + g * act) / time_constant[v];
}

extern "C" void kernel_launch(void* const* d_in, const int* in_sizes, int n_in,
                              void* d_out, int out_size, void* d_ws, size_t ws_size,
                              hipStream_t stream) {
    const float* rates         = (const float*)d_in[0];
    const float* weights       = (const float*)d_in[1];
    const float* gain          = (const float*)d_in[2];
    const float* time_constant = (const float*)d_in[3];
    const float* baseline      = (const float*)d_in[4];
    const float* ext_input     = (const float*)d_in[5];
    const int*   src           = (const int*)d_in[6];
    const int*   dst           = (const int*)d_in[7];
    const int*   is_input      = (const int*)d_in[8];
    float* out  = (float*)d_out;
    float* part = (float*)d_ws;

    // 80 chunks -> 240 blocks (1/CU at 133 KB LDS), 240 % 8 == 0 keeps the
    // XCD swizzle bijective and chunk-aligned (30 blocks = 10 chunks/XCD).
    // All candidates give edges_per_chunk % 16 == 0.
    static const int cand[] = {80, 40, 20, 10, 5, 4, 2, 1};
    int n_chunks = 1;
    for (int i = 0; i < (int)(sizeof(cand)/sizeof(cand[0])); ++i) {
        if ((size_t)cand[i] * N_NODES * sizeof(float) <= ws_size) { n_chunks = cand[i]; break; }
    }
    int edges_per_chunk = N_EDGES / n_chunks;

    int grid_e = K_BINS * n_chunks;
    edge_bin_kernel<<<grid_e, BLOCK, 0, stream>>>(rates, weights, src, dst,
                                                  part, n_chunks, edges_per_chunk);

    int block = 256;
    int grid_n = (N_NODES + block - 1) / block;
    node_kernel<<<grid_n, block, 0, stream>>>(rates, gain, time_constant, baseline,
                                              ext_input, is_input, part, out, n_chunks);
}

// Round 7
// 202.467 us; speedup vs baseline: 1.0961x; 1.0961x over previous
//
#include <hip/hip_runtime.h>
#include <math.h>

#define N_NODES 100000
#define N_EDGES 6400000
#define K_BINS  3
#define BIN_SZ  33336          // ceil(N_NODES/3) rounded to /4; 133,344 B LDS
#define BLOCK   1024
#define NXCD    8
#define LOG2_10 3.321928094887362f

// R7: keep R5's predicated structure (R6 proved predication protects the
// matched-only lane-work: branchless tripled gather+LDS lanes, +73% time).
// Cross-round analysis (R3=R5 at 2x waves, 1.67x scan volume; ~6cy/matched
// invariant) says the wall is per-CU L1 miss-handling on the divergent
// rates[] gather (26K random misses/CU x ~6cy = the whole 160K cycles).
// Two changes, same mechanism:
//   1. nontemporal gather -> bypass L1 allocation, straight to XCD-local L2.
//   2. phase-split: 16 predicated gathers into regs FIRST, then 16
//      predicated LDS atomics -> the 16 L2 round-trips overlap per iteration.
__global__ __launch_bounds__(BLOCK, 4) void edge_bin_kernel(
        const float* __restrict__ rates,
        const float* __restrict__ weights,
        const int* __restrict__ src,
        const int* __restrict__ dst,
        float* __restrict__ part,      // [n_chunks][N_NODES]
        int n_chunks, int edges_per_chunk) {
    __shared__ float bin[BIN_SZ];

    // Bijective XCD swizzle (m204): contiguous vbids per XCD => the 3 sibling
    // bin-blocks of a chunk share an XCD's L2 (R3-verified: FETCH 189->43 MB).
    const int nb  = gridDim.x;
    const int hb  = blockIdx.x;
    const int q   = nb / NXCD, r = nb % NXCD;
    const int xcd = hb % NXCD, pos = hb / NXCD;
    const int vbid = (xcd < r ? xcd * (q + 1) : r * (q + 1) + (xcd - r) * q) + pos;

    const int b = vbid % K_BINS;
    const int c = vbid / K_BINS;
    const int base_node = b * BIN_SZ;

    // Vectorized zero-init: 8334 float4 stores.
    {
        float4* bz = (float4*)bin;
        const float4 z = make_float4(0.f, 0.f, 0.f, 0.f);
        for (int i = threadIdx.x; i < (BIN_SZ >> 2); i += BLOCK) bz[i] = z;
    }
    __syncthreads();

    const long e0 = (long)c * edges_per_chunk;
    const int nq = edges_per_chunk >> 4;              // groups of 16 edges
    const int4*   s4 = (const int4*)(src + e0);
    const int4*   d4 = (const int4*)(dst + e0);
    const float4* w4 = (const float4*)(weights + e0);

// Phase-1 helper: match test + bin offset (no member access on macro args).
#define MATCH(dv, mo, eo)  unsigned eo = (unsigned)((dv) - base_node); \
                           bool mo = eo < BIN_SZ;
// Phase-2 helper: predicated nontemporal gather.
#define GATH(mo, av, ro)   float ro = 0.f; \
                           if (mo) ro = __builtin_nontemporal_load(rates + (av));

    for (int i = threadIdx.x; i < nq; i += BLOCK) {
        const int4*   dp = d4 + 4 * i;
        const int4*   sp = s4 + 4 * i;
        const float4* wp = w4 + 4 * i;
        int4   d0 = dp[0], d1 = dp[1], d2 = dp[2], d3 = dp[3];
        int4   sA = sp[0], sB = sp[1], sC = sp[2], sD = sp[3];
        float4 wA = wp[0], wB = wp[1], wC = wp[2], wD = wp[3];

        // Phase 1: 16 match tests + bin offsets.
        MATCH(d0.x, m0,  e0x) MATCH(d0.y, m1,  e1x)
        MATCH(d0.z, m2,  e2x) MATCH(d0.w, m3,  e3x)
        MATCH(d1.x, m4,  e4x) MATCH(d1.y, m5,  e5x)
        MATCH(d1.z, m6,  e6x) MATCH(d1.w, m7,  e7x)
        MATCH(d2.x, m8,  e8x) MATCH(d2.y, m9,  e9x)
        MATCH(d2.z, m10, e10x) MATCH(d2.w, m11, e11x)
        MATCH(d3.x, m12, e12x) MATCH(d3.y, m13, e13x)
        MATCH(d3.z, m14, e14x) MATCH(d3.w, m15, e15x)

        // Phase 2: 16 predicated gathers, all independent -> overlap in flight.
        GATH(m0,  sA.x, r0)  GATH(m1,  sA.y, r1)
        GATH(m2,  sA.z, r2)  GATH(m3,  sA.w, r3)
        GATH(m4,  sB.x, r4)  GATH(m5,  sB.y, r5)
        GATH(m6,  sB.z, r6)  GATH(m7,  sB.w, r7)
        GATH(m8,  sC.x, r8)  GATH(m9,  sC.y, r9)
        GATH(m10, sC.z, r10) GATH(m11, sC.w, r11)
        GATH(m12, sD.x, r12) GATH(m13, sD.y, r13)
        GATH(m14, sD.z, r14) GATH(m15, sD.w, r15)

        // Phase 3: 16 predicated LDS atomics (matched lanes only).
        if (m0)  atomicAdd(&bin[e0x],  r0  * wA.x);
        if (m1)  atomicAdd(&bin[e1x],  r1  * wA.y);
        if (m2)  atomicAdd(&bin[e2x],  r2  * wA.z);
        if (m3)  atomicAdd(&bin[e3x],  r3  * wA.w);
        if (m4)  atomicAdd(&bin[e4x],  r4  * wB.x);
        if (m5)  atomicAdd(&bin[e5x],  r5  * wB.y);
        if (m6)  atomicAdd(&bin[e6x],  r6  * wB.z);
        if (m7)  atomicAdd(&bin[e7x],  r7  * wB.w);
        if (m8)  atomicAdd(&bin[e8x],  r8  * wC.x);
        if (m9)  atomicAdd(&bin[e9x],  r9  * wC.y);
        if (m10) atomicAdd(&bin[e10x], r10 * wC.z);
        if (m11) atomicAdd(&bin[e11x], r11 * wC.w);
        if (m12) atomicAdd(&bin[e12x], r12 * wD.x);
        if (m13) atomicAdd(&bin[e13x], r13 * wD.y);
        if (m14) atomicAdd(&bin[e14x], r14 * wD.z);
        if (m15) atomicAdd(&bin[e15x], r15 * wD.w);
    }
#undef MATCH
#undef GATH
    __syncthreads();

    // Vectorized flush, CLAMPED to the row (last bin holds 33,328 nodes;
    // writing all BIN_SZ would race with the next chunk-row's bin-0 flush).
    const int flush_n = min(BIN_SZ, N_NODES - base_node);
    float4* outp = (float4*)(part + (size_t)c * N_NODES + base_node);
    const float4* binv = (const float4*)bin;
    for (int i = threadIdx.x; i < (flush_n >> 2); i += BLOCK) {
        outp[i] = binv[i];
    }
}

// Node epilogue: sum the n_chunks copies, then
// out[v] = (-r + 10^gain * tanh((is_input ? ext : syn) + baseline)) / tau
__global__ void node_kernel(const float* __restrict__ rates,
                            const float* __restrict__ gain,
                            const float* __restrict__ time_constant,
                            const float* __restrict__ baseline,
                            const float* __restrict__ ext_input,
                            const int*   __restrict__ is_input,
                            const float* __restrict__ part,
                            float* __restrict__ out,
                            int n_chunks) {
    int v = blockIdx.x * blockDim.x + threadIdx.x;
    if (v >= N_NODES) return;
    float s0 = 0.f, s1 = 0.f, s2 = 0.f, s3 = 0.f;
    float s4 = 0.f, s5 = 0.f, s6 = 0.f, s7 = 0.f;
    int k = 0;
    for (; k + 7 < n_chunks; k += 8) {
        s0 += part[(size_t)(k + 0) * N_NODES + v];
        s1 += part[(size_t)(k + 1) * N_NODES + v];
        s2 += part[(size_t)(k + 2) * N_NODES + v];
        s3 += part[(size_t)(k + 3) * N_NODES + v];
        s4 += part[(size_t)(k + 4) * N_NODES + v];
        s5 += part[(size_t)(k + 5) * N_NODES + v];
        s6 += part[(size_t)(k + 6) * N_NODES + v];
        s7 += part[(size_t)(k + 7) * N_NODES + v];
    }
    for (; k < n_chunks; ++k) s0 += part[(size_t)k * N_NODES + v];
    float s = ((s0 + s1) + (s2 + s3)) + ((s4 + s5) + (s6 + s7));
    float total = (is_input[v] != 0 ? ext_input[v] : s) + baseline[v];
    float act = tanhf(total);
    float g = exp2f(gain[v] * LOG2_10);   // 10^gain
    out[v] = (-rates[v] + g * act) / time_constant[v];
}

extern "C" void kernel_launch(void* const* d_in, const int* in_sizes, int n_in,
                              void* d_out, int out_size, void* d_ws, size_t ws_size,
                              hipStream_t stream) {
    const float* rates         = (const float*)d_in[0];
    const float* weights       = (const float*)d_in[1];
    const float* gain          = (const float*)d_in[2];
    const float* time_constant = (const float*)d_in[3];
    const float* baseline      = (const float*)d_in[4];
    const float* ext_input     = (const float*)d_in[5];
    const int*   src           = (const int*)d_in[6];
    const int*   dst           = (const int*)d_in[7];
    const int*   is_input      = (const int*)d_in[8];
    float* out  = (float*)d_out;
    float* part = (float*)d_ws;

    // 80 chunks -> 240 blocks (1/CU at 133 KB LDS), 240 % 8 == 0 keeps the
    // XCD swizzle bijective and chunk-aligned (30 blocks = 10 chunks/XCD).
    // All candidates give edges_per_chunk % 16 == 0.
    static const int cand[] = {80, 40, 20, 10, 5, 4, 2, 1};
    int n_chunks = 1;
    for (int i = 0; i < (int)(sizeof(cand)/sizeof(cand[0])); ++i) {
        if ((size_t)cand[i] * N_NODES * sizeof(float) <= ws_size) { n_chunks = cand[i]; break; }
    }
    int edges_per_chunk = N_EDGES / n_chunks;

    int grid_e = K_BINS * n_chunks;
    edge_bin_kernel<<<grid_e, BLOCK, 0, stream>>>(rates, weights, src, dst,
                                                  part, n_chunks, edges_per_chunk);

    int block = 256;
    int grid_n = (N_NODES + block - 1) / block;
    node_kernel<<<grid_n, block, 0, stream>>>(rates, gain, time_constant, baseline,
                                              ext_input, is_input, part, out, n_chunks);
}

// Round 8
// 169.792 us; speedup vs baseline: 1.3070x; 1.1924x over previous
//
#include <hip/hip_runtime.h>
#include <math.h>

#define N_NODES 100000
#define N_EDGES 6400000
#define K_BINS  3
#define BIN_SZ  33336          // ceil(N_NODES/3) rounded to /4; 133,344 B LDS
#define BLOCK   1024
#define NXCD    8
#define LOG2_10 3.321928094887362f

// R8 = revert to R5 (verified best: edge 67us, total 168.1us).
// Cost model fitted across R3/R5/R6/R7: edge time = per-CU lane-transaction
// processing: TA ~1.5cy/cache-line (42K lines/CU: 15K stream + 27K gather)
// + LDS-atomic ~2cy/lane (26.7K matched lanes/CU) + exec overhead.
//   - K-insensitive (R3=R5: lines/CU nearly equal) ✓
//   - R6 branchless: +53K dummy ds_add lanes x2cy = +49us ✓ (predication wins)
//   - R7 nontemporal: killed L2 retention (FETCH 39->64MB) = +30us ✓
// Structural floor for any binned design ~45-50us edge; alternatives
// (counting sort, compaction) move the same 6.4M gather-lines + 6.4M
// LDS-atomic lanes around without removing them.
__device__ __forceinline__ void proc4(const float* __restrict__ rates,
                                      float* __restrict__ bin, int base_node,
                                      int4 dd, int4 ss, float4 ww) {
    unsigned ex = (unsigned)(dd.x - base_node);
    unsigned ey = (unsigned)(dd.y - base_node);
    unsigned ez = (unsigned)(dd.z - base_node);
    unsigned ew = (unsigned)(dd.w - base_node);
    if (ex < BIN_SZ) atomicAdd(&bin[ex], rates[ss.x] * ww.x);
    if (ey < BIN_SZ) atomicAdd(&bin[ey], rates[ss.y] * ww.y);
    if (ez < BIN_SZ) atomicAdd(&bin[ez], rates[ss.z] * ww.z);
    if (ew < BIN_SZ) atomicAdd(&bin[ew], rates[ss.w] * ww.w);
}

__global__ __launch_bounds__(BLOCK) void edge_bin_kernel(
        const float* __restrict__ rates,
        const float* __restrict__ weights,
        const int* __restrict__ src,
        const int* __restrict__ dst,
        float* __restrict__ part,      // [n_chunks][N_NODES]
        int n_chunks, int edges_per_chunk) {
    __shared__ float bin[BIN_SZ];

    // Bijective XCD swizzle (m204): contiguous vbids per XCD => the 3 sibling
    // bin-blocks of a chunk share an XCD's L2 (R3-verified: FETCH 189->43 MB).
    const int nb  = gridDim.x;
    const int hb  = blockIdx.x;
    const int q   = nb / NXCD, r = nb % NXCD;
    const int xcd = hb % NXCD, pos = hb / NXCD;
    const int vbid = (xcd < r ? xcd * (q + 1) : r * (q + 1) + (xcd - r) * q) + pos;

    const int b = vbid % K_BINS;
    const int c = vbid / K_BINS;
    const int base_node = b * BIN_SZ;

    // Vectorized zero-init: 8334 float4 stores.
    {
        float4* bz = (float4*)bin;
        const float4 z = make_float4(0.f, 0.f, 0.f, 0.f);
        for (int i = threadIdx.x; i < (BIN_SZ >> 2); i += BLOCK) bz[i] = z;
    }
    __syncthreads();

    const long e0 = (long)c * edges_per_chunk;
    const int nq = edges_per_chunk >> 4;              // groups of 16 edges
    const int4*   s4 = (const int4*)(src + e0);
    const int4*   d4 = (const int4*)(dst + e0);
    const float4* w4 = (const float4*)(weights + e0);

    for (int i = threadIdx.x; i < nq; i += BLOCK) {
        const int4*   dp = d4 + 4 * i;
        const int4*   sp = s4 + 4 * i;
        const float4* wp = w4 + 4 * i;
        int4   d0 = dp[0], d1 = dp[1], d2 = dp[2], d3 = dp[3];
        int4   sA = sp[0], sB = sp[1], sC = sp[2], sD = sp[3];
        float4 wA = wp[0], wB = wp[1], wC = wp[2], wD = wp[3];
        proc4(rates, bin, base_node, d0, sA, wA);
        proc4(rates, bin, base_node, d1, sB, wB);
        proc4(rates, bin, base_node, d2, sC, wC);
        proc4(rates, bin, base_node, d3, sD, wD);
    }
    __syncthreads();

    // Vectorized flush, CLAMPED to the row (last bin holds 33,328 nodes;
    // writing all BIN_SZ would race with the next chunk-row's bin-0 flush).
    const int flush_n = min(BIN_SZ, N_NODES - base_node);
    float4* outp = (float4*)(part + (size_t)c * N_NODES + base_node);
    const float4* binv = (const float4*)bin;
    for (int i = threadIdx.x; i < (flush_n >> 2); i += BLOCK) {
        outp[i] = binv[i];
    }
}

// Node epilogue, float4-vectorized (R4-verified pattern; N_NODES % 4 == 0):
// sum the n_chunks copies, then
// out[v] = (-r + 10^gain * tanh((is_input ? ext : syn) + baseline)) / tau
__global__ void node_kernel(const float* __restrict__ rates,
                            const float* __restrict__ gain,
                            const float* __restrict__ time_constant,
                            const float* __restrict__ baseline,
                            const float* __restrict__ ext_input,
                            const int*   __restrict__ is_input,
                            const float* __restrict__ part,
                            float* __restrict__ out,
                            int n_chunks) {
    const int t = blockIdx.x * blockDim.x + threadIdx.x;  // group of 4 nodes
    if (t >= (N_NODES >> 2)) return;

    float4 a0 = make_float4(0.f, 0.f, 0.f, 0.f);
    float4 a1 = make_float4(0.f, 0.f, 0.f, 0.f);
    float4 a2 = make_float4(0.f, 0.f, 0.f, 0.f);
    float4 a3 = make_float4(0.f, 0.f, 0.f, 0.f);
    int k = 0;
    for (; k + 3 < n_chunks; k += 4) {
        float4 p0 = ((const float4*)(part + (size_t)(k + 0) * N_NODES))[t];
        float4 p1 = ((const float4*)(part + (size_t)(k + 1) * N_NODES))[t];
        float4 p2 = ((const float4*)(part + (size_t)(k + 2) * N_NODES))[t];
        float4 p3 = ((const float4*)(part + (size_t)(k + 3) * N_NODES))[t];
        a0.x += p0.x; a0.y += p0.y; a0.z += p0.z; a0.w += p0.w;
        a1.x += p1.x; a1.y += p1.y; a1.z += p1.z; a1.w += p1.w;
        a2.x += p2.x; a2.y += p2.y; a2.z += p2.z; a2.w += p2.w;
        a3.x += p3.x; a3.y += p3.y; a3.z += p3.z; a3.w += p3.w;
    }
    for (; k < n_chunks; ++k) {
        float4 p = ((const float4*)(part + (size_t)k * N_NODES))[t];
        a0.x += p.x; a0.y += p.y; a0.z += p.z; a0.w += p.w;
    }
    float sx = (a0.x + a1.x) + (a2.x + a3.x);
    float sy = (a0.y + a1.y) + (a2.y + a3.y);
    float sz = (a0.z + a1.z) + (a2.z + a3.z);
    float sw = (a0.w + a1.w) + (a2.w + a3.w);

    float4 r   = ((const float4*)rates)[t];
    float4 g   = ((const float4*)gain)[t];
    float4 tc  = ((const float4*)time_constant)[t];
    float4 bl  = ((const float4*)baseline)[t];
    float4 ext = ((const float4*)ext_input)[t];
    int4   ii  = ((const int4*)is_input)[t];

    float4 o;
    o.x = (-r.x + exp2f(g.x * LOG2_10) * tanhf((ii.x ? ext.x : sx) + bl.x)) / tc.x;
    o.y = (-r.y + exp2f(g.y * LOG2_10) * tanhf((ii.y ? ext.y : sy) + bl.y)) / tc.y;
    o.z = (-r.z + exp2f(g.z * LOG2_10) * tanhf((ii.z ? ext.z : sz) + bl.z)) / tc.z;
    o.w = (-r.w + exp2f(g.w * LOG2_10) * tanhf((ii.w ? ext.w : sw) + bl.w)) / tc.w;
    ((float4*)out)[t] = o;
}

extern "C" void kernel_launch(void* const* d_in, const int* in_sizes, int n_in,
                              void* d_out, int out_size, void* d_ws, size_t ws_size,
                              hipStream_t stream) {
    const float* rates         = (const float*)d_in[0];
    const float* weights       = (const float*)d_in[1];
    const float* gain          = (const float*)d_in[2];
    const float* time_constant = (const float*)d_in[3];
    const float* baseline      = (const float*)d_in[4];
    const float* ext_input     = (const float*)d_in[5];
    const int*   src           = (const int*)d_in[6];
    const int*   dst           = (const int*)d_in[7];
    const int*   is_input      = (const int*)d_in[8];
    float* out  = (float*)d_out;
    float* part = (float*)d_ws;

    // 80 chunks -> 240 blocks (1/CU at 133 KB LDS), 240 % 8 == 0 keeps the
    // XCD swizzle bijective and chunk-aligned (30 blocks = 10 chunks/XCD).
    // All candidates give edges_per_chunk % 16 == 0.
    static const int cand[] = {80, 40, 20, 10, 5, 4, 2, 1};
    int n_chunks = 1;
    for (int i = 0; i < (int)(sizeof(cand)/sizeof(cand[0])); ++i) {
        if ((size_t)cand[i] * N_NODES * sizeof(float) <= ws_size) { n_chunks = cand[i]; break; }
    }
    int edges_per_chunk = N_EDGES / n_chunks;

    int grid_e = K_BINS * n_chunks;
    edge_bin_kernel<<<grid_e, BLOCK, 0, stream>>>(rates, weights, src, dst,
                                                  part, n_chunks, edges_per_chunk);

    int block = 256;
    int grid_n = ((N_NODES >> 2) + block - 1) / block;   // 25,000 float4 groups
    node_kernel<<<grid_n, block, 0, stream>>>(rates, gain, time_constant, baseline,
                                              ext_input, is_input, part, out, n_chunks);
}

// Round 9
// 166.867 us; speedup vs baseline: 1.3299x; 1.0175x over previous
//
#include <hip/hip_runtime.h>
#include <math.h>

#define N_NODES 100000
#define N_EDGES 6400000
#define K_BINS  4
#define BIN_SZ  25000          // N_NODES / 4 exactly; 100,000 B LDS -> 1 block/CU
#define BLOCK   1024
#define NXCD    8
#define LOG2_10 3.321928094887362f

// R9: K=4 bins x P=64 chunks -> grid = 256 = exactly 1 block per CU
// (R8's 240 blocks left 16 CUs idle). Structure identical to the verified
// R5/R8 kernel; parameter-only change.
// Cost model (fitted R3/R5/R6/R7/R8): edge time = per-CU lane-transaction
// processing: TA ~1.5cy/cache-line (stream + divergent gather) + LDS-atomic
// ~2cy/matched-lane. K=3->4: stream +25%, gather/LDS -6%, CU coverage +6.7%.
// Side benefit: part shrinks 32 -> 25.6 MB (node reads -20%).
__device__ __forceinline__ void proc4(const float* __restrict__ rates,
                                      float* __restrict__ bin, int base_node,
                                      int4 dd, int4 ss, float4 ww) {
    unsigned ex = (unsigned)(dd.x - base_node);
    unsigned ey = (unsigned)(dd.y - base_node);
    unsigned ez = (unsigned)(dd.z - base_node);
    unsigned ew = (unsigned)(dd.w - base_node);
    if (ex < BIN_SZ) atomicAdd(&bin[ex], rates[ss.x] * ww.x);
    if (ey < BIN_SZ) atomicAdd(&bin[ey], rates[ss.y] * ww.y);
    if (ez < BIN_SZ) atomicAdd(&bin[ez], rates[ss.z] * ww.z);
    if (ew < BIN_SZ) atomicAdd(&bin[ew], rates[ss.w] * ww.w);
}

__global__ __launch_bounds__(BLOCK) void edge_bin_kernel(
        const float* __restrict__ rates,
        const float* __restrict__ weights,
        const int* __restrict__ src,
        const int* __restrict__ dst,
        float* __restrict__ part,      // [n_chunks][N_NODES]
        int n_chunks, int edges_per_chunk) {
    __shared__ float bin[BIN_SZ];

    // Bijective XCD swizzle (m204): contiguous vbids per XCD => the 4 sibling
    // bin-blocks of a chunk share an XCD's L2 (R3-verified: FETCH 189->43 MB).
    // grid=256: 32 blocks = 8 whole chunks per XCD.
    const int nb  = gridDim.x;
    const int hb  = blockIdx.x;
    const int q   = nb / NXCD, r = nb % NXCD;
    const int xcd = hb % NXCD, pos = hb / NXCD;
    const int vbid = (xcd < r ? xcd * (q + 1) : r * (q + 1) + (xcd - r) * q) + pos;

    const int b = vbid % K_BINS;
    const int c = vbid / K_BINS;
    const int base_node = b * BIN_SZ;

    // Vectorized zero-init: 6250 float4 stores.
    {
        float4* bz = (float4*)bin;
        const float4 z = make_float4(0.f, 0.f, 0.f, 0.f);
        for (int i = threadIdx.x; i < (BIN_SZ >> 2); i += BLOCK) bz[i] = z;
    }
    __syncthreads();

    const long e0 = (long)c * edges_per_chunk;
    const int nq = edges_per_chunk >> 4;              // groups of 16 edges
    const int4*   s4 = (const int4*)(src + e0);
    const int4*   d4 = (const int4*)(dst + e0);
    const float4* w4 = (const float4*)(weights + e0);

    for (int i = threadIdx.x; i < nq; i += BLOCK) {
        const int4*   dp = d4 + 4 * i;
        const int4*   sp = s4 + 4 * i;
        const float4* wp = w4 + 4 * i;
        int4   d0 = dp[0], d1 = dp[1], d2 = dp[2], d3 = dp[3];
        int4   sA = sp[0], sB = sp[1], sC = sp[2], sD = sp[3];
        float4 wA = wp[0], wB = wp[1], wC = wp[2], wD = wp[3];
        proc4(rates, bin, base_node, d0, sA, wA);
        proc4(rates, bin, base_node, d1, sB, wB);
        proc4(rates, bin, base_node, d2, sC, wC);
        proc4(rates, bin, base_node, d3, sD, wD);
    }
    __syncthreads();

    // Vectorized flush (K=4: 4*25000 == N_NODES, clamp is a no-op but kept
    // for safety against future K changes).
    const int flush_n = min(BIN_SZ, N_NODES - base_node);
    float4* outp = (float4*)(part + (size_t)c * N_NODES + base_node);
    const float4* binv = (const float4*)bin;
    for (int i = threadIdx.x; i < (flush_n >> 2); i += BLOCK) {
        outp[i] = binv[i];
    }
}

// Node epilogue, float4-vectorized (N_NODES % 4 == 0): sum the n_chunks
// copies, then out[v] = (-r + 10^gain * tanh((is_input?ext:syn)+baseline))/tau
__global__ void node_kernel(const float* __restrict__ rates,
                            const float* __restrict__ gain,
                            const float* __restrict__ time_constant,
                            const float* __restrict__ baseline,
                            const float* __restrict__ ext_input,
                            const int*   __restrict__ is_input,
                            const float* __restrict__ part,
                            float* __restrict__ out,
                            int n_chunks) {
    const int t = blockIdx.x * blockDim.x + threadIdx.x;  // group of 4 nodes
    if (t >= (N_NODES >> 2)) return;

    float4 a0 = make_float4(0.f, 0.f, 0.f, 0.f);
    float4 a1 = make_float4(0.f, 0.f, 0.f, 0.f);
    float4 a2 = make_float4(0.f, 0.f, 0.f, 0.f);
    float4 a3 = make_float4(0.f, 0.f, 0.f, 0.f);
    int k = 0;
    for (; k + 3 < n_chunks; k += 4) {
        float4 p0 = ((const float4*)(part + (size_t)(k + 0) * N_NODES))[t];
        float4 p1 = ((const float4*)(part + (size_t)(k + 1) * N_NODES))[t];
        float4 p2 = ((const float4*)(part + (size_t)(k + 2) * N_NODES))[t];
        float4 p3 = ((const float4*)(part + (size_t)(k + 3) * N_NODES))[t];
        a0.x += p0.x; a0.y += p0.y; a0.z += p0.z; a0.w += p0.w;
        a1.x += p1.x; a1.y += p1.y; a1.z += p1.z; a1.w += p1.w;
        a2.x += p2.x; a2.y += p2.y; a2.z += p2.z; a2.w += p2.w;
        a3.x += p3.x; a3.y += p3.y; a3.z += p3.z; a3.w += p3.w;
    }
    for (; k < n_chunks; ++k) {
        float4 p = ((const float4*)(part + (size_t)k * N_NODES))[t];
        a0.x += p.x; a0.y += p.y; a0.z += p.z; a0.w += p.w;
    }
    float sx = (a0.x + a1.x) + (a2.x + a3.x);
    float sy = (a0.y + a1.y) + (a2.y + a3.y);
    float sz = (a0.z + a1.z) + (a2.z + a3.z);
    float sw = (a0.w + a1.w) + (a2.w + a3.w);

    float4 r   = ((const float4*)rates)[t];
    float4 g   = ((const float4*)gain)[t];
    float4 tc  = ((const float4*)time_constant)[t];
    float4 bl  = ((const float4*)baseline)[t];
    float4 ext = ((const float4*)ext_input)[t];
    int4   ii  = ((const int4*)is_input)[t];

    float4 o;
    o.x = (-r.x + exp2f(g.x * LOG2_10) * tanhf((ii.x ? ext.x : sx) + bl.x)) / tc.x;
    o.y = (-r.y + exp2f(g.y * LOG2_10) * tanhf((ii.y ? ext.y : sy) + bl.y)) / tc.y;
    o.z = (-r.z + exp2f(g.z * LOG2_10) * tanhf((ii.z ? ext.z : sz) + bl.z)) / tc.z;
    o.w = (-r.w + exp2f(g.w * LOG2_10) * tanhf((ii.w ? ext.w : sw) + bl.w)) / tc.w;
    ((float4*)out)[t] = o;
}

extern "C" void kernel_launch(void* const* d_in, const int* in_sizes, int n_in,
                              void* d_out, int out_size, void* d_ws, size_t ws_size,
                              hipStream_t stream) {
    const float* rates         = (const float*)d_in[0];
    const float* weights       = (const float*)d_in[1];
    const float* gain          = (const float*)d_in[2];
    const float* time_constant = (const float*)d_in[3];
    const float* baseline      = (const float*)d_in[4];
    const float* ext_input     = (const float*)d_in[5];
    const int*   src           = (const int*)d_in[6];
    const int*   dst           = (const int*)d_in[7];
    const int*   is_input      = (const int*)d_in[8];
    float* out  = (float*)d_out;
    float* part = (float*)d_ws;

    // 64 chunks -> grid 4*64 = 256 blocks = exactly 1/CU at 100 KB LDS.
    // 256 % 8 == 0 keeps the XCD swizzle bijective and chunk-aligned
    // (32 blocks = 8 whole chunks per XCD). All candidates give
    // edges_per_chunk % 16 == 0. part needs 64*400KB = 25.6 MB of ws.
    static const int cand[] = {64, 32, 16, 8, 4, 2, 1};
    int n_chunks = 1;
    for (int i = 0; i < (int)(sizeof(cand)/sizeof(cand[0])); ++i) {
        if ((size_t)cand[i] * N_NODES * sizeof(float) <= ws_size) { n_chunks = cand[i]; break; }
    }
    int edges_per_chunk = N_EDGES / n_chunks;

    int grid_e = K_BINS * n_chunks;
    edge_bin_kernel<<<grid_e, BLOCK, 0, stream>>>(rates, weights, src, dst,
                                                  part, n_chunks, edges_per_chunk);

    int block = 256;
    int grid_n = ((N_NODES >> 2) + block - 1) / block;   // 25,000 float4 groups
    node_kernel<<<grid_n, block, 0, stream>>>(rates, gain, time_constant, baseline,
                                              ext_input, is_input, part, out, n_chunks);
}